// Round 1
// baseline (21.085 us; speedup 1.0000x reference)
//
#include <hip/hip_runtime.h>
#include <hip/hip_bf16.h>

#define VOCAB 32000
#define EMBED 128
#define NTOK  (4 * 2048)

// out[t][d] = W[d * VOCAB + e[t]] + b[d]
// One thread handles 4 consecutive dims of one token -> float4 coalesced store.
// 32 threads per token; reads of W are scattered (stride 128KB) but W (16MB)
// lives in L2/L3 across replays.
__global__ __launch_bounds__(256) void embed_kernel(const int* __restrict__ e,
                                                    const float* __restrict__ W,
                                                    const float* __restrict__ bias,
                                                    float* __restrict__ out) {
    int gid = blockIdx.x * blockDim.x + threadIdx.x;   // 0 .. NTOK*32-1
    int t    = gid >> 5;          // token index (32 threads per token)
    int dsub = (gid & 31) << 2;   // starting dim (0,4,...,124)
    if (t >= NTOK) return;

    int tok = e[t];

    float4 r;
    r.x = W[(dsub + 0) * VOCAB + tok] + bias[dsub + 0];
    r.y = W[(dsub + 1) * VOCAB + tok] + bias[dsub + 1];
    r.z = W[(dsub + 2) * VOCAB + tok] + bias[dsub + 2];
    r.w = W[(dsub + 3) * VOCAB + tok] + bias[dsub + 3];

    *reinterpret_cast<float4*>(&out[t * EMBED + dsub]) = r;
}

extern "C" void kernel_launch(void* const* d_in, const int* in_sizes, int n_in,
                              void* d_out, int out_size, void* d_ws, size_t ws_size,
                              hipStream_t stream) {
    const int*   e    = (const int*)d_in[0];
    const float* W    = (const float*)d_in[1];
    const float* bias = (const float*)d_in[2];
    float*       out  = (float*)d_out;

    const int threads = NTOK * (EMBED / 4);       // 262144
    const int block = 256;
    const int grid = (threads + block - 1) / block;  // 1024
    embed_kernel<<<grid, block, 0, stream>>>(e, W, bias, out);
}

// Round 2
// 10.140 us; speedup vs baseline: 2.0793x; 2.0793x over previous
//
#include <hip/hip_runtime.h>
#include <hip/hip_bf16.h>

#define VOCAB 32000
#define EMBED 128
#define NTOK  (4 * 2048)
#define TV    64            // vocab columns per block
#define PITCH 129           // LDS pitch (floats) -> conflict-free
#define CHUNK 2048          // tokens scanned per phase (worst-case match capacity)

// out[t][:] = W[:, e[t]] + bias.  W is [EMBED][VOCAB] row-major, so embedding
// vectors are strided columns. Instead of gathering (scattered reads), each
// block streams a coalesced [EMBED][TV] tile of W into LDS (transposed), then
// scans all token ids and writes the full 512B output row for every token
// whose id falls in this block's vocab range. Each token matches exactly one
// block -> full output coverage. W is read exactly once, coalesced.
__global__ __launch_bounds__(256) void embed_tile(const int* __restrict__ e,
                                                  const float* __restrict__ W,
                                                  const float* __restrict__ bias,
                                                  float* __restrict__ out) {
    __shared__ float ldsT[TV * PITCH];   // ldsT[c*PITCH + d] = W[d][v0+c]
    __shared__ float lbias[EMBED];
    __shared__ int   matches[CHUNK];     // packed (t<<6)|c
    __shared__ int   nmatch;

    const int tid = threadIdx.x;
    const int v0  = blockIdx.x * TV;

    if (tid < EMBED) lbias[tid] = bias[tid];

    // Stage W tile, transposed into LDS.
    // Thread reads float4 at row d = tid/16 + 16*it, cols v0 + 4*(tid%16).
    // LDS writes: bank = (516*c' + 129*i + d) % 32 -> max 2-way (free).
    {
        const int c4 = (tid & 15) * 4;
        const int dr = tid >> 4;
        #pragma unroll
        for (int it = 0; it < 8; ++it) {
            int d = dr + it * 16;
            float4 w = *reinterpret_cast<const float4*>(&W[d * VOCAB + v0 + c4]);
            ldsT[(c4 + 0) * PITCH + d] = w.x;
            ldsT[(c4 + 1) * PITCH + d] = w.y;
            ldsT[(c4 + 2) * PITCH + d] = w.z;
            ldsT[(c4 + 3) * PITCH + d] = w.w;
        }
    }
    __syncthreads();

    const int dsub = (tid & 31) << 2;    // this thread's 4 dims within a token row

    for (int chunk = 0; chunk < NTOK; chunk += CHUNK) {
        if (tid == 0) nmatch = 0;
        __syncthreads();

        // Scan CHUNK token ids: 8 per thread via two int4 loads.
        {
            const int base = chunk + tid * 8;
            int4 a = *reinterpret_cast<const int4*>(&e[base]);
            int4 b = *reinterpret_cast<const int4*>(&e[base + 4]);
            int tok[8] = {a.x, a.y, a.z, a.w, b.x, b.y, b.z, b.w};
            #pragma unroll
            for (int j = 0; j < 8; ++j) {
                unsigned c = (unsigned)(tok[j] - v0);
                if (c < TV) {
                    int idx = atomicAdd(&nmatch, 1);
                    matches[idx] = ((base + j) << 6) | (int)c;
                }
            }
        }
        __syncthreads();

        // Emit: 32 threads per matched token, float4 each.
        const int nm = nmatch;
        for (int m = tid >> 5; m < nm; m += 8) {
            int packed = matches[m];
            int t = packed >> 6;
            int c = packed & (TV - 1);
            const float* col = &ldsT[c * PITCH + dsub];
            float4 r;
            r.x = col[0] + lbias[dsub + 0];
            r.y = col[1] + lbias[dsub + 1];
            r.z = col[2] + lbias[dsub + 2];
            r.w = col[3] + lbias[dsub + 3];
            *reinterpret_cast<float4*>(&out[t * EMBED + dsub]) = r;
        }
        __syncthreads();
    }
}

extern "C" void kernel_launch(void* const* d_in, const int* in_sizes, int n_in,
                              void* d_out, int out_size, void* d_ws, size_t ws_size,
                              hipStream_t stream) {
    const int*   e    = (const int*)d_in[0];
    const float* W    = (const float*)d_in[1];
    const float* bias = (const float*)d_in[2];
    float*       out  = (float*)d_out;

    const int grid = VOCAB / TV;   // 500 blocks
    embed_tile<<<grid, 256, 0, stream>>>(e, W, bias, out);
}